// Round 5
// baseline (125.108 us; speedup 1.0000x reference)
//
#include <hip/hip_runtime.h>
#include <math.h>

// Problem constants (match reference setup_inputs)
#define B 32
#define S 4096
#define E 256
#define H 256
#define T 64
#define J (T - 2)

// Kernel 1 (proven streamer, unchanged from R3): d[row] = dot(enc[row,:], We).
// One 64-lane wave per row; lane i handles float4 at element 4*i (E=256=64*4).
// Whole grid sweeps memory linearly -> HBM-friendly.
__global__ __launch_bounds__(256) void row_dot_kernel(
    const float* __restrict__ enc,
    const float* __restrict__ We,
    float* __restrict__ d) {
    const int gid  = blockIdx.x * blockDim.x + threadIdx.x;
    const int row  = gid >> 6;          // wave index == row index
    const int lane = threadIdx.x & 63;

    const float4* rowp = reinterpret_cast<const float4*>(enc + (size_t)row * E);
    const float4  v = rowp[lane];
    const float4  w = reinterpret_cast<const float4*>(We)[lane];
    float p = v.x * w.x + v.y * w.y + v.z * w.z + v.w * w.w;

#pragma unroll
    for (int off = 32; off >= 1; off >>= 1)
        p += __shfl_xor(p, off, 64);

    if (lane == 0) d[row] = p;
}

// Kernel 2 (fused tail, ONE block, no atomics): segment means for all 2048
// segments (reads d from L2; per-thread loads are all independent -> ILP),
// then loss[b,j] = LSE_{m=j+2..T-1}(tt[b,m]) - tt[b,j+2] over 1984 parallel
// items, deterministic block reduce, out[0] = mean.
__global__ __launch_bounds__(256) void tail_kernel(
    const float* __restrict__ d,
    const int* __restrict__ ends,
    float* __restrict__ out) {
    const int tid = threadIdx.x;

    __shared__ float tt[B * T];   // 8 KB: segment means
    __shared__ float partial[4];

    // 2048 segments / 256 threads = 8 segments per thread; every load
    // independent -> deep pipelining against L2 latency.
#pragma unroll
    for (int k = 0; k < 8; ++k) {
        const int g   = tid + k * 256;        // b*T + tau
        const int tau = g & (T - 1);
        const int b   = g >> 6;
        const int e   = ends[g];
        const int st  = (tau == 0) ? 0 : (ends[g - 1] + 1);
        const float* db = d + (size_t)b * S;
        float s = 0.0f;
        for (int i = st; i <= e; ++i) s += db[i];
        tt[g] = s / (float)(e - st + 1);
    }
    __syncthreads();

    // 1984 (b,j) items over 256 threads.
    float sum = 0.0f;
    for (int item = tid; item < B * J; item += 256) {
        const int b = item / J;
        const int j = item - b * J;
        const float* tb = tt + b * T;
        float M = -1e30f;
        for (int m = j + 2; m < T; ++m) M = fmaxf(M, tb[m]);
        float a = 0.0f;
        for (int m = j + 2; m < T; ++m) a += __expf(tb[m] - M);
        sum += logf(a) + M - tb[j + 2];
    }

#pragma unroll
    for (int off = 32; off >= 1; off >>= 1)
        sum += __shfl_xor(sum, off, 64);
    if ((tid & 63) == 0) partial[tid >> 6] = sum;
    __syncthreads();
    if (tid == 0)
        out[0] = (partial[0] + partial[1] + partial[2] + partial[3])
               / (float)(B * J);
}

extern "C" void kernel_launch(void* const* d_in, const int* in_sizes, int n_in,
                              void* d_out, int out_size, void* d_ws, size_t ws_size,
                              hipStream_t stream) {
    // Inputs: 0 encoder_output (B,S,E) f32; 1 his_turn_end_ids (B,T) i32;
    // 2..5 LSTM weights (algebraically dead); 6 fc_w (1,H+E); 7 fc_b (dead).
    // loss[b,j] = LSE_{m=j+2..T-1}(t[b,m]) - t[b,j+2], t = seg_mean(enc) @ We,
    // We = fc_w[0, H:]. LSTM path and fc_b cancel inside LSE - logits[...,0].
    const float* enc  = (const float*)d_in[0];
    const int*   ends = (const int*)d_in[1];
    const float* We   = (const float*)d_in[6] + H;

    float* d   = (float*)d_ws;   // B*S floats = 512 KiB
    float* out = (float*)d_out;

    row_dot_kernel<<<(B * S) / 4, 256, 0, stream>>>(enc, We, d);
    tail_kernel<<<1, 256, 0, stream>>>(d, ends, out);
}

// Round 6
// 47.795 us; speedup vs baseline: 2.6176x; 2.6176x over previous
//
#include <hip/hip_runtime.h>
#include <math.h>

// Problem constants (match reference setup_inputs)
#define B 32
#define S 4096
#define E 256
#define H 256
#define T 64
#define J (T - 2)
#define PADF 32  // floats per segment accumulator slot (128 B: one cache line)

// Kernel 1: streaming row-dot + direct segment accumulation.
// One 64-lane wave per row (proven BW-optimal pattern). After the in-wave
// reduce, lane 0 atomically adds the row's dot into its segment's padded
// accumulator. Segment lookup is ONE ballot: T==64==wave width, so lane l
// holds ends[b,l] and tau = popcount(ends < r).
// 32768 atomics / 2048 distinct cache lines = 16 per line x ~75ns, spread
// across the kernel's ~15us -> negligible (R4 measured 75ns/same-line atomic).
__global__ __launch_bounds__(256) void row_dot_seg_kernel(
    const float* __restrict__ enc,
    const int* __restrict__ ends,
    const float* __restrict__ We,
    float* __restrict__ segacc) {
    const int gid  = blockIdx.x * blockDim.x + threadIdx.x;
    const int row  = gid >> 6;          // global row = b*S + r
    const int lane = threadIdx.x & 63;
    const int b    = row >> 12;         // S == 4096 rows per batch
    const int r    = row & (S - 1);

    const float4 v = reinterpret_cast<const float4*>(enc + (size_t)row * E)[lane];
    const float4 w = reinterpret_cast<const float4*>(We)[lane];
    float p = fmaf(v.x, w.x, fmaf(v.y, w.y, fmaf(v.z, w.z, v.w * w.w)));

#pragma unroll
    for (int off = 32; off >= 1; off >>= 1)
        p += __shfl_xor(p, off, 64);

    // Segment index: ends[b,:] ascending, ends[b,T-1]==S-1 >= r always.
    const int e_l = ends[b * T + lane];               // coalesced, L1/L2-hot
    const unsigned long long blt = __ballot(e_l < r);
    const int tau = __popcll(blt);

    if (lane == 0)
        atomicAdd(&segacc[(size_t)(b * T + tau) * PADF], p);
}

// Kernel 2: tiny tail, one block. Means from segacc, then per-b suffix-LSE
// scan (validated in R4), reduce to mean.
__global__ __launch_bounds__(256) void tail2_kernel(
    const float* __restrict__ segacc,
    const int* __restrict__ ends,
    float* __restrict__ out) {
    const int tid = threadIdx.x;

    __shared__ int   el[B * T];
    __shared__ float tt[B * T];
    __shared__ float pl[B];

#pragma unroll
    for (int k = 0; k < 8; ++k) el[tid + k * 256] = ends[tid + k * 256];
    __syncthreads();

#pragma unroll
    for (int k = 0; k < 8; ++k) {
        const int g   = tid + k * 256;      // b*T + tau
        const int tau = g & (T - 1);
        const int st  = (tau == 0) ? 0 : (el[g - 1] + 1);
        const int len = el[g] - st + 1;
        tt[g] = segacc[(size_t)g * PADF] / (float)len;
    }
    __syncthreads();

    if (tid < B) {
        const float* tb = tt + tid * T;
        // Suffix LSE scan: state (M, a) = logsumexp over tb[j+2 .. T-1].
        float M = tb[T - 1], a = 1.0f, ls = 0.0f;
        for (int j = J - 1; j >= 0; --j) {
            ls += logf(a) + M - tb[j + 2];
            if (j > 0) {
                const float x  = tb[j + 1];
                const float M2 = fmaxf(M, x);
                a = a * __expf(M - M2) + __expf(x - M2);
                M = M2;
            }
        }
        pl[tid] = ls;
    }
    __syncthreads();

    if (tid < 64) {  // wave 0
        float s = (tid < B) ? pl[tid] : 0.0f;
#pragma unroll
        for (int off = 32; off >= 1; off >>= 1)
            s += __shfl_xor(s, off, 64);
        if (tid == 0) out[0] = s / (float)(B * J);
    }
}

extern "C" void kernel_launch(void* const* d_in, const int* in_sizes, int n_in,
                              void* d_out, int out_size, void* d_ws, size_t ws_size,
                              hipStream_t stream) {
    // Inputs: 0 encoder_output (B,S,E) f32; 1 his_turn_end_ids (B,T) i32;
    // 2..5 LSTM weights (algebraically dead); 6 fc_w (1,H+E); 7 fc_b (dead).
    // loss[b,j] = LSE_{m=j+2..T-1}(t[b,m]) - t[b,j+2], t = seg_mean(enc) @ We,
    // We = fc_w[0, H:]. LSTM path and fc_b cancel inside LSE - logits[...,0].
    const float* enc  = (const float*)d_in[0];
    const int*   ends = (const int*)d_in[1];
    const float* We   = (const float*)d_in[6] + H;

    float* segacc = (float*)d_ws;   // B*T*PADF floats = 256 KiB
    float* out    = (float*)d_out;

    hipMemsetAsync(segacc, 0, (size_t)B * T * PADF * sizeof(float), stream);
    row_dot_seg_kernel<<<(B * S) / 4, 256, 0, stream>>>(enc, ends, We, segacc);
    tail2_kernel<<<1, 256, 0, stream>>>(segacc, ends, out);
}